// Round 1
// baseline (1642.615 us; speedup 1.0000x reference)
//
#include <hip/hip_runtime.h>
#include <math.h>

#define N_NODES 100000
#define N_EDGES 3200000
#define FIN     1433

// ---------------- zero ----------------
__global__ void k_zero(int* __restrict__ p, int n) {
  int i = blockIdx.x * blockDim.x + threadIdx.x;
  if (i < n) p[i] = 0;
}

// ---------------- histogram of destinations (int4 reads) ----------------
__global__ void k_hist(const int* __restrict__ row, int* __restrict__ cnt) {
  int e4 = blockIdx.x * blockDim.x + threadIdx.x;
  if (e4 * 4 < N_EDGES) {  // N_EDGES % 4 == 0
    int4 r = *(const int4*)(row + e4 * 4);
    atomicAdd(&cnt[r.x], 1);
    atomicAdd(&cnt[r.y], 1);
    atomicAdd(&cnt[r.z], 1);
    atomicAdd(&cnt[r.w], 1);
  }
}

// ---------------- scanA: per-block sums; also dinv = 1/sqrt(deg+1) ----------------
__global__ void k_scanA(const int* __restrict__ cnt, int* __restrict__ bsum,
                        float* __restrict__ dinv) {
  __shared__ int sd[256];
  int t = threadIdx.x, b = blockIdx.x;
  int base = b * 1024 + t * 4;  // N_NODES % 4 == 0 -> granule fully in or out
  int s = 0;
  if (base < N_NODES) {
    int4 v = *(const int4*)(cnt + base);
    s = v.x + v.y + v.z + v.w;
    float4 d;
    d.x = 1.0f / sqrtf((float)(v.x + 1));
    d.y = 1.0f / sqrtf((float)(v.y + 1));
    d.z = 1.0f / sqrtf((float)(v.z + 1));
    d.w = 1.0f / sqrtf((float)(v.w + 1));
    *(float4*)(dinv + base) = d;
  }
  sd[t] = s; __syncthreads();
  for (int off = 128; off > 0; off >>= 1) {
    if (t < off) sd[t] += sd[t + off];
    __syncthreads();
  }
  if (t == 0) bsum[b] = sd[0];
}

__global__ void k_scanB(int* __restrict__ bsum, int* __restrict__ rowStart, int nb) {
  __shared__ int sd[128];
  int t = threadIdx.x;
  int v = (t < nb) ? bsum[t] : 0;
  sd[t] = v;
  __syncthreads();
  for (int off = 1; off < 128; off <<= 1) {
    int add = (t >= off) ? sd[t - off] : 0;
    __syncthreads();
    sd[t] += add;
    __syncthreads();
  }
  if (t < nb) bsum[t] = (t == 0) ? 0 : sd[t - 1];
  if (t == 0) rowStart[N_NODES] = sd[nb - 1];
}

// ---------------- scanC: rowStart; also fill = rowStart (scatter cursors) ----------
__global__ void k_scanC(const int* __restrict__ cnt, const int* __restrict__ bsum,
                        int* __restrict__ rowStart, int* __restrict__ fill) {
  __shared__ int sd[256];
  int t = threadIdx.x, b = blockIdx.x;
  int base = b * 1024 + t * 4;
  int4 v = make_int4(0, 0, 0, 0);
  if (base < N_NODES) v = *(const int4*)(cnt + base);
  int s = v.x + v.y + v.z + v.w;
  sd[t] = s; __syncthreads();
  for (int off = 1; off < 256; off <<= 1) {
    int add = (t >= off) ? sd[t - off] : 0;
    __syncthreads();
    sd[t] += add;
    __syncthreads();
  }
  int ex = (t == 0) ? 0 : sd[t - 1];
  int base0 = bsum[b] + ex;
  if (base < N_NODES) {
    int4 rs;
    rs.x = base0;
    rs.y = rs.x + v.x;
    rs.z = rs.y + v.y;
    rs.w = rs.z + v.z;
    *(int4*)(rowStart + base) = rs;
    *(int4*)(fill + base) = rs;
  }
}

// ---------------- scatter edges into CSR (fill pre-seeded with rowStart) ----------
__global__ void k_scatter(const int* __restrict__ row, const int* __restrict__ col,
                          int* __restrict__ fill, int* __restrict__ colc) {
  int e = blockIdx.x * blockDim.x + threadIdx.x;
  if (e < N_EDGES) {
    int pos = atomicAdd(&fill[row[e]], 1);
    colc[pos] = col[e];
  }
}

// ---------------- GEMM1: t1s = dinv .* (x @ W1) ----------------
// 4-wave K-split per 64-row group: wave w handles chunks w, w+4, ..., each chunk
// 32 k-values (128 B contiguous per lane), register double-buffered. Partials
// combined through LDS. 4x the wave count of thread-per-row (6252 waves) for
// latency hiding; dinv scaling folded into the epilogue write.
__global__ __launch_bounds__(256) void k_gemm1(const float* __restrict__ x,
                                               const float* __restrict__ W1,
                                               const float* __restrict__ dinv,
                                               float* __restrict__ t1s) {
  __shared__ float sd[4][64][16];
  int lane = threadIdx.x & 63;
  int wid  = threadIdx.x >> 6;
  int rowi = blockIdx.x * 64 + lane;

  float acc[16];
#pragma unroll
  for (int j = 0; j < 16; j++) acc[j] = 0.0f;

  if (rowi < N_NODES) {
    const float* __restrict__ xr = x + (size_t)rowi * FIN;
    float4 buf[8], nbuf[8];
    {
      const float* p = xr + wid * 32;
#pragma unroll
      for (int m = 0; m < 8; m++) buf[m] = *(const float4*)(p + m * 4);
    }
    for (int it = 0; it < 11; it++) {
      int kc = (it * 4 + wid) * 32;
      if (it < 10) {
        const float* p = xr + kc + 128;
#pragma unroll
        for (int m = 0; m < 8; m++) nbuf[m] = *(const float4*)(p + m * 4);
      }
#pragma unroll
      for (int m = 0; m < 8; m++) {
        float xv0 = buf[m].x, xv1 = buf[m].y, xv2 = buf[m].z, xv3 = buf[m].w;
        const float* w0 = &W1[(size_t)(kc + m * 4 + 0) * 16];
        const float* w1 = &W1[(size_t)(kc + m * 4 + 1) * 16];
        const float* w2 = &W1[(size_t)(kc + m * 4 + 2) * 16];
        const float* w3 = &W1[(size_t)(kc + m * 4 + 3) * 16];
#pragma unroll
        for (int j = 0; j < 16; j++) {
          acc[j] = fmaf(xv0, w0[j], acc[j]);
          acc[j] = fmaf(xv1, w1[j], acc[j]);
          acc[j] = fmaf(xv2, w2[j], acc[j]);
          acc[j] = fmaf(xv3, w3[j], acc[j]);
        }
      }
#pragma unroll
      for (int m = 0; m < 8; m++) buf[m] = nbuf[m];
    }
    if (wid == 3) {  // tail k = 1408..1432
      for (int k = 1408; k < FIN; k++) {
        float xv = xr[k];
        const float* wv = &W1[(size_t)k * 16];
#pragma unroll
        for (int j = 0; j < 16; j++) acc[j] = fmaf(xv, wv[j], acc[j]);
      }
    }
  }

#pragma unroll
  for (int j = 0; j < 16; j += 4)
    *(float4*)(&sd[wid][lane][j]) = make_float4(acc[j], acc[j + 1], acc[j + 2], acc[j + 3]);
  __syncthreads();

  // thread (lane, wid) reduces row=lane, cols wid*4..wid*4+3 across the 4 partials
  int r2 = blockIdx.x * 64 + lane;
  if (r2 < N_NODES) {
    float4 s0 = *(const float4*)(&sd[0][lane][wid * 4]);
    float4 s1 = *(const float4*)(&sd[1][lane][wid * 4]);
    float4 s2 = *(const float4*)(&sd[2][lane][wid * 4]);
    float4 s3 = *(const float4*)(&sd[3][lane][wid * 4]);
    float di = dinv[r2];
    float4 o;
    o.x = di * ((s0.x + s1.x) + (s2.x + s3.x));
    o.y = di * ((s0.y + s1.y) + (s2.y + s3.y));
    o.z = di * ((s0.z + s1.z) + (s2.z + s3.z));
    o.w = di * ((s0.w + s1.w) + (s2.w + s3.w));
    *(float4*)(t1s + (size_t)r2 * 16 + wid * 4) = o;
  }
}

// ---------------- agg1 (+ fused GEMM2): t2s = dinv .* (relu(di*(sum + self) + b1) @ W2)
// Wave per node; 4 lanes per edge (float4 slices), 16 edge slots. t1s is
// pre-scaled by dinv -> per-edge work is a pure float4 gather + add (no dinv
// gather, no fma). Epilogue: lanes 0..3 hold the 16 h-values; the 16x7 W2
// product is computed with a 4-lane shuffle reduce, eliminating the h1r
// round-trip and the separate gemm2 kernel.
__global__ __launch_bounds__(256) void k_agg1(const float* __restrict__ t1s,
                                              const int* __restrict__ rowStart,
                                              const int* __restrict__ colc,
                                              const float* __restrict__ dinv,
                                              const float* __restrict__ b1,
                                              const float* __restrict__ W2,
                                              float* __restrict__ t2s) {
  int lane = threadIdx.x & 63;
  int wid  = threadIdx.x >> 6;
  int node = blockIdx.x * 4 + wid;
  if (node >= N_NODES) return;
  int q = lane & 3, slot = lane >> 2;
  int s0 = rowStart[node], s1 = rowStart[node + 1];
  float ax = 0.f, ay = 0.f, az = 0.f, aw = 0.f;
  for (int e = s0 + slot; e < s1; e += 16) {
    int c = colc[e];
    float4 v = *(const float4*)(t1s + (size_t)c * 16 + q * 4);
    ax += v.x; ay += v.y; az += v.z; aw += v.w;
  }
#pragma unroll
  for (int off = 4; off < 64; off <<= 1) {
    ax += __shfl_xor(ax, off, 64);
    ay += __shfl_xor(ay, off, 64);
    az += __shfl_xor(az, off, 64);
    aw += __shfl_xor(aw, off, 64);
  }
  if (slot == 0) {  // lanes 0..3
    float di = dinv[node];
    float4 sv = *(const float4*)(t1s + (size_t)node * 16 + q * 4);
    float4 bb = *(const float4*)(b1 + q * 4);
    float h0 = fmaxf(0.f, di * (ax + sv.x) + bb.x);
    float h1 = fmaxf(0.f, di * (ay + sv.y) + bb.y);
    float h2 = fmaxf(0.f, di * (az + sv.z) + bb.z);
    float h3 = fmaxf(0.f, di * (aw + sv.w) + bb.w);
    // partial of h @ W2 over rows 4q..4q+3
    float p[8];
#pragma unroll
    for (int j = 0; j < 7; j++) {
      const float* wr = W2 + (size_t)(4 * q) * 7 + j;
      p[j] = h0 * wr[0] + h1 * wr[7] + h2 * wr[14] + h3 * wr[21];
    }
    p[7] = 0.f;
#pragma unroll
    for (int j = 0; j < 8; j++) {
      p[j] += __shfl_xor(p[j], 1, 64);
      p[j] += __shfl_xor(p[j], 2, 64);
    }
    if (q < 2) {
      float4 o = make_float4(di * p[4 * q + 0], di * p[4 * q + 1],
                             di * p[4 * q + 2], di * p[4 * q + 3]);
      *(float4*)(t2s + (size_t)node * 8 + q * 4) = o;
    }
  }
}

// ---------------- agg2 + bias + log_softmax -> out ----------------
// Wave per node; 2 lanes per edge (float4 halves of padded 8), 32 edge slots.
// t2s pre-scaled by dinv -> pure gather + add per edge.
__global__ __launch_bounds__(256) void k_agg2(const float* __restrict__ t2s,
                                              const int* __restrict__ rowStart,
                                              const int* __restrict__ colc,
                                              const float* __restrict__ dinv,
                                              const float* __restrict__ b2,
                                              float* __restrict__ out) {
  int lane = threadIdx.x & 63;
  int wid  = threadIdx.x >> 6;
  int node = blockIdx.x * 4 + wid;
  if (node >= N_NODES) return;
  int q = lane & 1, slot = lane >> 1;
  int s0 = rowStart[node], s1 = rowStart[node + 1];
  float ax = 0.f, ay = 0.f, az = 0.f, aw = 0.f;
  for (int e = s0 + slot; e < s1; e += 32) {
    int c = colc[e];
    float4 v = *(const float4*)(t2s + (size_t)c * 8 + q * 4);
    ax += v.x; ay += v.y; az += v.z; aw += v.w;
  }
#pragma unroll
  for (int off = 2; off < 64; off <<= 1) {
    ax += __shfl_xor(ax, off, 64);
    ay += __shfl_xor(ay, off, 64);
    az += __shfl_xor(az, off, 64);
    aw += __shfl_xor(aw, off, 64);
  }
  float di = dinv[node];
  float4 sv = *(const float4*)(t2s + (size_t)node * 8 + q * 4);
  float lg[4];
  float am[4] = {ax, ay, az, aw};
  float sm[4] = {sv.x, sv.y, sv.z, sv.w};
#pragma unroll
  for (int m = 0; m < 4; m++) {
    int j = 4 * q + m;
    float bb = (j < 7) ? b2[j] : 0.0f;
    lg[m] = di * (am[m] + sm[m]) + bb;
    if (j == 7) lg[m] = -1e30f;
  }
  // exchange halves: q=0 lanes receive logits 4..6 from q=1 partner
  float o4 = __shfl_xor(lg[0], 1, 64);
  float o5 = __shfl_xor(lg[1], 1, 64);
  float o6 = __shfl_xor(lg[2], 1, 64);
  if (lane == 0) {
    float a[7] = {lg[0], lg[1], lg[2], lg[3], o4, o5, o6};
    float mx = a[0];
#pragma unroll
    for (int j = 1; j < 7; j++) mx = fmaxf(mx, a[j]);
    float s = 0.f;
#pragma unroll
    for (int j = 0; j < 7; j++) s += expf(a[j] - mx);
    float lse = mx + logf(s);
    float* o = out + (size_t)node * 7;
#pragma unroll
    for (int j = 0; j < 7; j++) o[j] = a[j] - lse;
  }
}

extern "C" void kernel_launch(void* const* d_in, const int* in_sizes, int n_in,
                              void* d_out, int out_size, void* d_ws, size_t ws_size,
                              hipStream_t stream) {
  const float* x   = (const float*)d_in[0];
  const int*   row = (const int*)d_in[1];
  const int*   col = (const int*)d_in[2];
  const float* W1  = (const float*)d_in[3];
  const float* b1  = (const float*)d_in[4];
  const float* W2  = (const float*)d_in[5];
  const float* b2  = (const float*)d_in[6];
  float* out = (float*)d_out;

  char* w = (char*)d_ws;
  auto alloc = [&](size_t bytes) {
    char* p = w;
    w += (bytes + 255) & ~(size_t)255;
    return p;
  };
  int*   cnt      = (int*)alloc((size_t)N_NODES * 4);
  int*   fill     = (int*)alloc((size_t)N_NODES * 4);
  int*   rowStart = (int*)alloc((size_t)(N_NODES + 1) * 4);
  int*   bsum     = (int*)alloc(128 * 4);
  float* dinv     = (float*)alloc((size_t)N_NODES * 4);
  int*   colc     = (int*)alloc((size_t)N_EDGES * 4);
  float* t1s      = (float*)alloc((size_t)N_NODES * 16 * 4);
  float* t2s      = (float*)alloc((size_t)N_NODES * 8 * 4);

  const int NB = (N_NODES + 1023) / 1024;  // 98

  k_zero<<<(N_NODES + 255) / 256, 256, 0, stream>>>(cnt, N_NODES);
  k_hist<<<(N_EDGES / 4 + 255) / 256, 256, 0, stream>>>(row, cnt);
  k_scanA<<<NB, 256, 0, stream>>>(cnt, bsum, dinv);
  k_scanB<<<1, 128, 0, stream>>>(bsum, rowStart, NB);
  k_scanC<<<NB, 256, 0, stream>>>(cnt, bsum, rowStart, fill);
  k_scatter<<<(N_EDGES + 255) / 256, 256, 0, stream>>>(row, col, fill, colc);
  k_gemm1<<<(N_NODES + 63) / 64, 256, 0, stream>>>(x, W1, dinv, t1s);
  k_agg1<<<(N_NODES + 3) / 4, 256, 0, stream>>>(t1s, rowStart, colc, dinv, b1, W2, t2s);
  k_agg2<<<(N_NODES + 3) / 4, 256, 0, stream>>>(t2s, rowStart, colc, dinv, b2, out);
}

// Round 2
// 1508.108 us; speedup vs baseline: 1.0892x; 1.0892x over previous
//
#include <hip/hip_runtime.h>
#include <math.h>

#define N_NODES 100000
#define N_EDGES 3200000
#define FIN     1433

// ---------------- zero ----------------
__global__ void k_zero(int* __restrict__ p, int n) {
  int i = blockIdx.x * blockDim.x + threadIdx.x;
  if (i < n) p[i] = 0;
}

// ---------------- histogram of destinations (int4 reads) ----------------
__global__ void k_hist(const int* __restrict__ row, int* __restrict__ cnt) {
  int e4 = blockIdx.x * blockDim.x + threadIdx.x;
  if (e4 * 4 < N_EDGES) {  // N_EDGES % 4 == 0
    int4 r = *(const int4*)(row + e4 * 4);
    atomicAdd(&cnt[r.x], 1);
    atomicAdd(&cnt[r.y], 1);
    atomicAdd(&cnt[r.z], 1);
    atomicAdd(&cnt[r.w], 1);
  }
}

// ---------------- scanA: per-block sums; also dinv = 1/sqrt(deg+1) ----------------
__global__ void k_scanA(const int* __restrict__ cnt, int* __restrict__ bsum,
                        float* __restrict__ dinv) {
  __shared__ int sd[256];
  int t = threadIdx.x, b = blockIdx.x;
  int base = b * 1024 + t * 4;
  int s = 0;
  if (base < N_NODES) {
    int4 v = *(const int4*)(cnt + base);
    s = v.x + v.y + v.z + v.w;
    float4 d;
    d.x = 1.0f / sqrtf((float)(v.x + 1));
    d.y = 1.0f / sqrtf((float)(v.y + 1));
    d.z = 1.0f / sqrtf((float)(v.z + 1));
    d.w = 1.0f / sqrtf((float)(v.w + 1));
    *(float4*)(dinv + base) = d;
  }
  sd[t] = s; __syncthreads();
  for (int off = 128; off > 0; off >>= 1) {
    if (t < off) sd[t] += sd[t + off];
    __syncthreads();
  }
  if (t == 0) bsum[b] = sd[0];
}

__global__ void k_scanB(int* __restrict__ bsum, int* __restrict__ rowStart, int nb) {
  __shared__ int sd[128];
  int t = threadIdx.x;
  int v = (t < nb) ? bsum[t] : 0;
  sd[t] = v;
  __syncthreads();
  for (int off = 1; off < 128; off <<= 1) {
    int add = (t >= off) ? sd[t - off] : 0;
    __syncthreads();
    sd[t] += add;
    __syncthreads();
  }
  if (t < nb) bsum[t] = (t == 0) ? 0 : sd[t - 1];
  if (t == 0) rowStart[N_NODES] = sd[nb - 1];
}

// ---------------- scanC: rowStart; also fill = rowStart (scatter cursors) ----------
__global__ void k_scanC(const int* __restrict__ cnt, const int* __restrict__ bsum,
                        int* __restrict__ rowStart, int* __restrict__ fill) {
  __shared__ int sd[256];
  int t = threadIdx.x, b = blockIdx.x;
  int base = b * 1024 + t * 4;
  int4 v = make_int4(0, 0, 0, 0);
  if (base < N_NODES) v = *(const int4*)(cnt + base);
  int s = v.x + v.y + v.z + v.w;
  sd[t] = s; __syncthreads();
  for (int off = 1; off < 256; off <<= 1) {
    int add = (t >= off) ? sd[t - off] : 0;
    __syncthreads();
    sd[t] += add;
    __syncthreads();
  }
  int ex = (t == 0) ? 0 : sd[t - 1];
  int base0 = bsum[b] + ex;
  if (base < N_NODES) {
    int4 rs;
    rs.x = base0;
    rs.y = rs.x + v.x;
    rs.z = rs.y + v.y;
    rs.w = rs.z + v.z;
    *(int4*)(rowStart + base) = rs;
    *(int4*)(fill + base) = rs;
  }
}

// ---------------- scatter edges into CSR (fill pre-seeded with rowStart) ----------
__global__ void k_scatter(const int* __restrict__ row, const int* __restrict__ col,
                          int* __restrict__ fill, int* __restrict__ colc) {
  int e = blockIdx.x * blockDim.x + threadIdx.x;
  if (e < N_EDGES) {
    int pos = atomicAdd(&fill[row[e]], 1);
    colc[pos] = col[e];
  }
}

// ---------------- GEMM1: t1s = dinv .* (x @ W1) ----------------
// One wave per block, 64 rows. Per 64-wide K-tile:
//   stage: instruction i loads row i at k=lane -> 64-lane consecutive dwords
//          (256 B coalesced bursts), 64 independent loads per thread in flight
//          (16 KB per wave) -> HBM-saturating.
//   LDS:   transposed tile xT[k][row] with quad-XOR swizzle (quad q of row-space
//          stored at q^(k&15)) -> ds_write_b128 x16 and ds_read_b128 both
//          bank-conflict-free.
//   compute: thread owns rows rq*4..rq*4+3 x cols cq*4..cq*4+3 (rq=lane&15,
//          cq=lane>>4). Per k: one b128 LDS read (4 rows), one 16B W1 load
//          (imm-offset, L1-resident), 16 FMAs.
// Single-wave block: no barriers needed (in-order LDS unit, lockstep wave).
// launch_bounds(64,1): allow ~130 VGPRs (vbuf 64 + acc 16) without spill;
// occupancy is grid-limited (1563 blocks = 6.1/CU) so regs are free.
__global__ __launch_bounds__(64, 1) void k_gemm1(const float* __restrict__ x,
                                                 const float* __restrict__ W1,
                                                 const float* __restrict__ dinv,
                                                 float* __restrict__ t1s) {
  __shared__ float xT[64 * 64];  // 16 KB, [k][swizzled row]
  const int lane  = threadIdx.x;       // 0..63 (= k index when staging)
  const int rbase = blockIdx.x * 64;
  const int rq    = lane & 15;         // row-quad owned in compute (and k&15 when staging)
  const int cq    = lane >> 4;         // col-quad owned in compute
  const bool full = (rbase + 64 <= N_NODES);

  float vbuf[64];
  float acc[4][4];
#pragma unroll
  for (int a = 0; a < 4; a++)
#pragma unroll
    for (int b = 0; b < 4; b++) acc[a][b] = 0.0f;

  // ---- prologue: stage tile 0 (k = lane) ----
  {
    const float* p = x + (size_t)rbase * FIN + lane;
    if (full) {
#pragma unroll
      for (int i = 0; i < 64; i++) vbuf[i] = p[(size_t)i * FIN];
    } else {
#pragma unroll
      for (int i = 0; i < 64; i++)
        vbuf[i] = (rbase + i < N_NODES) ? p[(size_t)i * FIN] : 0.0f;
    }
  }

  for (int t = 0; t < 23; t++) {
    // ---- write staged tile to LDS (transposed, quad-swizzled) ----
    // thread holds (row i, k=lane); stores to xT[lane*64 + ((i>>2)^(lane&15))*4 + (i&3)]
#pragma unroll
    for (int q = 0; q < 16; q++) {
      *(float4*)&xT[(lane << 6) + ((q ^ rq) << 2)] =
          make_float4(vbuf[4 * q + 0], vbuf[4 * q + 1], vbuf[4 * q + 2], vbuf[4 * q + 3]);
    }

    const float* wbase = W1 + (size_t)(t * 64) * 16 + (cq << 2);

    if (t < 22) {
      // ---- prefetch next tile (overlaps with compute below) ----
      const int kk = (t + 1) * 64 + lane;
      const bool kv = (kk < FIN);  // only relevant for t+1 == 22 (lane < 25)
      const float* p = x + (size_t)rbase * FIN + kk;
      if (kv && full) {
#pragma unroll
        for (int i = 0; i < 64; i++) vbuf[i] = p[(size_t)i * FIN];
      } else {
#pragma unroll
        for (int i = 0; i < 64; i++)
          vbuf[i] = (kv && (rbase + i < N_NODES)) ? p[(size_t)i * FIN] : 0.0f;
      }
      // ---- compute full 64-k tile from LDS ----
#pragma unroll 16
      for (int k = 0; k < 64; k++) {
        float4 xv = *(const float4*)&xT[(k << 6) + ((rq ^ (k & 15)) << 2)];
        float4 wv = *(const float4*)&wbase[(size_t)k * 16];
        acc[0][0] = fmaf(xv.x, wv.x, acc[0][0]);
        acc[0][1] = fmaf(xv.x, wv.y, acc[0][1]);
        acc[0][2] = fmaf(xv.x, wv.z, acc[0][2]);
        acc[0][3] = fmaf(xv.x, wv.w, acc[0][3]);
        acc[1][0] = fmaf(xv.y, wv.x, acc[1][0]);
        acc[1][1] = fmaf(xv.y, wv.y, acc[1][1]);
        acc[1][2] = fmaf(xv.y, wv.z, acc[1][2]);
        acc[1][3] = fmaf(xv.y, wv.w, acc[1][3]);
        acc[2][0] = fmaf(xv.z, wv.x, acc[2][0]);
        acc[2][1] = fmaf(xv.z, wv.y, acc[2][1]);
        acc[2][2] = fmaf(xv.z, wv.z, acc[2][2]);
        acc[2][3] = fmaf(xv.z, wv.w, acc[2][3]);
        acc[3][0] = fmaf(xv.w, wv.x, acc[3][0]);
        acc[3][1] = fmaf(xv.w, wv.y, acc[3][1]);
        acc[3][2] = fmaf(xv.w, wv.z, acc[3][2]);
        acc[3][3] = fmaf(xv.w, wv.w, acc[3][3]);
      }
    } else {
      // ---- tail tile: k = 1408..1432 (25 valid, rest staged as zeros) ----
#pragma unroll
      for (int k = 0; k < 25; k++) {
        float4 xv = *(const float4*)&xT[(k << 6) + ((rq ^ (k & 15)) << 2)];
        float4 wv = *(const float4*)&wbase[(size_t)k * 16];
        acc[0][0] = fmaf(xv.x, wv.x, acc[0][0]);
        acc[0][1] = fmaf(xv.x, wv.y, acc[0][1]);
        acc[0][2] = fmaf(xv.x, wv.z, acc[0][2]);
        acc[0][3] = fmaf(xv.x, wv.w, acc[0][3]);
        acc[1][0] = fmaf(xv.y, wv.x, acc[1][0]);
        acc[1][1] = fmaf(xv.y, wv.y, acc[1][1]);
        acc[1][2] = fmaf(xv.y, wv.z, acc[1][2]);
        acc[1][3] = fmaf(xv.y, wv.w, acc[1][3]);
        acc[2][0] = fmaf(xv.z, wv.x, acc[2][0]);
        acc[2][1] = fmaf(xv.z, wv.y, acc[2][1]);
        acc[2][2] = fmaf(xv.z, wv.z, acc[2][2]);
        acc[2][3] = fmaf(xv.z, wv.w, acc[2][3]);
        acc[3][0] = fmaf(xv.w, wv.x, acc[3][0]);
        acc[3][1] = fmaf(xv.w, wv.y, acc[3][1]);
        acc[3][2] = fmaf(xv.w, wv.z, acc[3][2]);
        acc[3][3] = fmaf(xv.w, wv.w, acc[3][3]);
      }
    }
  }

  // ---- epilogue: scale by dinv, store ----
#pragma unroll
  for (int rr = 0; rr < 4; rr++) {
    int r = rbase + (rq << 2) + rr;
    if (r < N_NODES) {
      float di = dinv[r];
      *(float4*)&t1s[(size_t)r * 16 + (cq << 2)] =
          make_float4(di * acc[rr][0], di * acc[rr][1], di * acc[rr][2], di * acc[rr][3]);
    }
  }
}

// ---------------- agg1 (+ fused GEMM2): t2s = dinv .* (relu(di*(sum + self) + b1) @ W2)
__global__ __launch_bounds__(256) void k_agg1(const float* __restrict__ t1s,
                                              const int* __restrict__ rowStart,
                                              const int* __restrict__ colc,
                                              const float* __restrict__ dinv,
                                              const float* __restrict__ b1,
                                              const float* __restrict__ W2,
                                              float* __restrict__ t2s) {
  int lane = threadIdx.x & 63;
  int wid  = threadIdx.x >> 6;
  int node = blockIdx.x * 4 + wid;
  if (node >= N_NODES) return;
  int q = lane & 3, slot = lane >> 2;
  int s0 = rowStart[node], s1 = rowStart[node + 1];
  float ax = 0.f, ay = 0.f, az = 0.f, aw = 0.f;
  for (int e = s0 + slot; e < s1; e += 16) {
    int c = colc[e];
    float4 v = *(const float4*)(t1s + (size_t)c * 16 + q * 4);
    ax += v.x; ay += v.y; az += v.z; aw += v.w;
  }
#pragma unroll
  for (int off = 4; off < 64; off <<= 1) {
    ax += __shfl_xor(ax, off, 64);
    ay += __shfl_xor(ay, off, 64);
    az += __shfl_xor(az, off, 64);
    aw += __shfl_xor(aw, off, 64);
  }
  if (slot == 0) {  // lanes 0..3
    float di = dinv[node];
    float4 sv = *(const float4*)(t1s + (size_t)node * 16 + q * 4);
    float4 bb = *(const float4*)(b1 + q * 4);
    float h0 = fmaxf(0.f, di * (ax + sv.x) + bb.x);
    float h1 = fmaxf(0.f, di * (ay + sv.y) + bb.y);
    float h2 = fmaxf(0.f, di * (az + sv.z) + bb.z);
    float h3 = fmaxf(0.f, di * (aw + sv.w) + bb.w);
    float p[8];
#pragma unroll
    for (int j = 0; j < 7; j++) {
      const float* wr = W2 + (size_t)(4 * q) * 7 + j;
      p[j] = h0 * wr[0] + h1 * wr[7] + h2 * wr[14] + h3 * wr[21];
    }
    p[7] = 0.f;
#pragma unroll
    for (int j = 0; j < 8; j++) {
      p[j] += __shfl_xor(p[j], 1, 64);
      p[j] += __shfl_xor(p[j], 2, 64);
    }
    if (q < 2) {
      float4 o = make_float4(di * p[4 * q + 0], di * p[4 * q + 1],
                             di * p[4 * q + 2], di * p[4 * q + 3]);
      *(float4*)(t2s + (size_t)node * 8 + q * 4) = o;
    }
  }
}

// ---------------- agg2 + bias + log_softmax -> out ----------------
__global__ __launch_bounds__(256) void k_agg2(const float* __restrict__ t2s,
                                              const int* __restrict__ rowStart,
                                              const int* __restrict__ colc,
                                              const float* __restrict__ dinv,
                                              const float* __restrict__ b2,
                                              float* __restrict__ out) {
  int lane = threadIdx.x & 63;
  int wid  = threadIdx.x >> 6;
  int node = blockIdx.x * 4 + wid;
  if (node >= N_NODES) return;
  int q = lane & 1, slot = lane >> 1;
  int s0 = rowStart[node], s1 = rowStart[node + 1];
  float ax = 0.f, ay = 0.f, az = 0.f, aw = 0.f;
  for (int e = s0 + slot; e < s1; e += 32) {
    int c = colc[e];
    float4 v = *(const float4*)(t2s + (size_t)c * 8 + q * 4);
    ax += v.x; ay += v.y; az += v.z; aw += v.w;
  }
#pragma unroll
  for (int off = 2; off < 64; off <<= 1) {
    ax += __shfl_xor(ax, off, 64);
    ay += __shfl_xor(ay, off, 64);
    az += __shfl_xor(az, off, 64);
    aw += __shfl_xor(aw, off, 64);
  }
  float di = dinv[node];
  float4 sv = *(const float4*)(t2s + (size_t)node * 8 + q * 4);
  float lg[4];
  float am[4] = {ax, ay, az, aw};
  float sm[4] = {sv.x, sv.y, sv.z, sv.w};
#pragma unroll
  for (int m = 0; m < 4; m++) {
    int j = 4 * q + m;
    float bb = (j < 7) ? b2[j] : 0.0f;
    lg[m] = di * (am[m] + sm[m]) + bb;
    if (j == 7) lg[m] = -1e30f;
  }
  float o4 = __shfl_xor(lg[0], 1, 64);
  float o5 = __shfl_xor(lg[1], 1, 64);
  float o6 = __shfl_xor(lg[2], 1, 64);
  if (lane == 0) {
    float a[7] = {lg[0], lg[1], lg[2], lg[3], o4, o5, o6};
    float mx = a[0];
#pragma unroll
    for (int j = 1; j < 7; j++) mx = fmaxf(mx, a[j]);
    float s = 0.f;
#pragma unroll
    for (int j = 0; j < 7; j++) s += expf(a[j] - mx);
    float lse = mx + logf(s);
    float* o = out + (size_t)node * 7;
#pragma unroll
    for (int j = 0; j < 7; j++) o[j] = a[j] - lse;
  }
}

extern "C" void kernel_launch(void* const* d_in, const int* in_sizes, int n_in,
                              void* d_out, int out_size, void* d_ws, size_t ws_size,
                              hipStream_t stream) {
  const float* x   = (const float*)d_in[0];
  const int*   row = (const int*)d_in[1];
  const int*   col = (const int*)d_in[2];
  const float* W1  = (const float*)d_in[3];
  const float* b1  = (const float*)d_in[4];
  const float* W2  = (const float*)d_in[5];
  const float* b2  = (const float*)d_in[6];
  float* out = (float*)d_out;

  char* w = (char*)d_ws;
  auto alloc = [&](size_t bytes) {
    char* p = w;
    w += (bytes + 255) & ~(size_t)255;
    return p;
  };
  int*   cnt      = (int*)alloc((size_t)N_NODES * 4);
  int*   fill     = (int*)alloc((size_t)N_NODES * 4);
  int*   rowStart = (int*)alloc((size_t)(N_NODES + 1) * 4);
  int*   bsum     = (int*)alloc(128 * 4);
  float* dinv     = (float*)alloc((size_t)N_NODES * 4);
  int*   colc     = (int*)alloc((size_t)N_EDGES * 4);
  float* t1s      = (float*)alloc((size_t)N_NODES * 16 * 4);
  float* t2s      = (float*)alloc((size_t)N_NODES * 8 * 4);

  const int NB = (N_NODES + 1023) / 1024;  // 98

  k_zero<<<(N_NODES + 255) / 256, 256, 0, stream>>>(cnt, N_NODES);
  k_hist<<<(N_EDGES / 4 + 255) / 256, 256, 0, stream>>>(row, cnt);
  k_scanA<<<NB, 256, 0, stream>>>(cnt, bsum, dinv);
  k_scanB<<<1, 128, 0, stream>>>(bsum, rowStart, NB);
  k_scanC<<<NB, 256, 0, stream>>>(cnt, bsum, rowStart, fill);
  k_scatter<<<(N_EDGES + 255) / 256, 256, 0, stream>>>(row, col, fill, colc);
  k_gemm1<<<(N_NODES + 63) / 64, 64, 0, stream>>>(x, W1, dinv, t1s);
  k_agg1<<<(N_NODES + 3) / 4, 256, 0, stream>>>(t1s, rowStart, colc, dinv, b1, W2, t2s);
  k_agg2<<<(N_NODES + 3) / 4, 256, 0, stream>>>(t2s, rowStart, colc, dinv, b2, out);
}